// Round 1
// baseline (116.264 us; speedup 1.0000x reference)
//
#include <hip/hip_runtime.h>

// ContextGuidedTokenShift on MI355X.
// x: (B=8, N=16384, C=576) f32, H=W=128. out = w*shift(x) + (1-w)*x
// Channel slabs (widths all multiples of 16) each have a fixed (dy,dx):
//   c in [0,256):   slab = c>>6           (4 slabs of 64)
//   c in [256,512): slab = 4 + (c-256)>>5 (8 slabs of 32)
//   c in [512,576): slab = 12 + (c-512)>>4 (4 slabs of 16)
// shifted[y,x] = in[y-dy, x-dx] if in bounds else 0.

#define B_   8
#define HW_  128
#define N_   16384      // HW_*HW_
#define C_   576
#define C4_  144        // C_/4

__constant__ signed char g_dy[16] = {0, 0, 1, -1,  0,  0, 2, -2,  1, -1,  1, -1,  2, -2,  2, -2};
__constant__ signed char g_dx[16] = {1, -1, 0, 0,  2, -2, 0,  0,  1, -1, -1,  1,  2, -2, -2,  2};

__global__ __launch_bounds__(256) void cgts_kernel(const float* __restrict__ in,
                                                   const float* __restrict__ wptr,
                                                   float* __restrict__ out,
                                                   int total4) {
    const int idx = blockIdx.x * 256 + threadIdx.x;
    if (idx >= total4) return;

    const float w   = wptr[0];
    const float omw = 1.0f - w;

    // decompose flat float4 index -> (b, token, channel4)
    const int c4 = idx % C4_;          // magic-mul division
    const int t  = idx / C4_;          // b*N + n
    const int n  = t & (N_ - 1);
    const int b  = t >> 14;            // N_ = 2^14
    const int y  = n >> 7;             // HW_ = 2^7
    const int xc = n & (HW_ - 1);
    const int c  = c4 << 2;

    // slab index -> offset
    int s;
    if (c < 256)      s = c >> 6;
    else if (c < 512) s = 4 + ((c - 256) >> 5);
    else              s = 12 + ((c - 512) >> 4);
    const int dy = (int)g_dy[s];
    const int dx = (int)g_dx[s];

    // self load: flat float index = 4*idx (fully contiguous across the grid)
    const float4 self = *reinterpret_cast<const float4*>(in + (size_t)idx * 4);

    const int sy = y - dy;
    const int sx = xc - dx;
    float4 sh = make_float4(0.f, 0.f, 0.f, 0.f);
    if ((unsigned)sy < (unsigned)HW_ && (unsigned)sx < (unsigned)HW_) {
        const size_t sidx = ((size_t)(b * N_ + (sy << 7) + sx)) * C_ + c;
        sh = *reinterpret_cast<const float4*>(in + sidx);
    }

    float4 o;
    o.x = w * sh.x + omw * self.x;
    o.y = w * sh.y + omw * self.y;
    o.z = w * sh.z + omw * self.z;
    o.w = w * sh.w + omw * self.w;
    *reinterpret_cast<float4*>(out + (size_t)idx * 4) = o;
}

extern "C" void kernel_launch(void* const* d_in, const int* in_sizes, int n_in,
                              void* d_out, int out_size, void* d_ws, size_t ws_size,
                              hipStream_t stream) {
    const float* x = (const float*)d_in[0];
    const float* w = (const float*)d_in[1];
    float* out = (float*)d_out;

    const int total4 = B_ * N_ * C4_;          // 18,874,368 float4 chunks
    const int blocks = (total4 + 255) / 256;   // 73,728
    cgts_kernel<<<blocks, 256, 0, stream>>>(x, w, out, total4);
}

// Round 3
// 108.440 us; speedup vs baseline: 1.0722x; 1.0722x over previous
//
#include <hip/hip_runtime.h>

// ContextGuidedTokenShift on MI355X.
// x: (B=8, N=16384, C=576) f32, H=W=128. out = w*shift(x) + (1-w)*x
// Channel slabs (widths all multiples of 16) each have a fixed (dy,dx):
//   c in [0,256):   slab = c>>6            (4 slabs of 64)
//   c in [256,512): slab = 4 + (c-256)>>5  (8 slabs of 32)
//   c in [512,576): slab = 12 + (c-512)>>4 (4 slabs of 16)
// shifted[y,x] = in[y-dy, x-dx] if in bounds else 0.
//
// R3: same as R2 (XCD-aware swizzle + NT streaming stores) but with a native
// clang ext_vector float4 so __builtin_nontemporal_store compiles.

#define B_   8
#define HW_  128
#define N_   16384      // HW_*HW_
#define C_   576
#define C4_  144        // C_/4
#define NXCD 8

typedef float f32x4 __attribute__((ext_vector_type(4)));

__constant__ signed char g_dy[16] = {0, 0, 1, -1,  0,  0, 2, -2,  1, -1,  1, -1,  2, -2,  2, -2};
__constant__ signed char g_dx[16] = {1, -1, 0, 0,  2, -2, 0,  0,  1, -1, -1,  1,  2, -2, -2,  2};

__global__ __launch_bounds__(256) void cgts_kernel(const float* __restrict__ in,
                                                   const float* __restrict__ wptr,
                                                   float* __restrict__ out) {
    // XCD-aware swizzle: hardware dispatches blockIdx round-robin across the
    // 8 XCDs; remap so XCD k processes a contiguous chunk of the index space.
    // grid = 73728 blocks, divisible by 8 -> bijective.
    const int bid = blockIdx.x;
    const int swz = (bid & (NXCD - 1)) * (int)(gridDim.x / NXCD) + (bid >> 3);
    const int idx = swz * 256 + (int)threadIdx.x;   // float4 index

    const float w   = wptr[0];
    const float omw = 1.0f - w;

    // decompose flat float4 index -> (b, token, channel4)
    const int c4 = idx % C4_;          // magic-mul division
    const int t  = idx / C4_;          // b*N + n
    const int n  = t & (N_ - 1);
    const int b  = t >> 14;            // N_ = 2^14
    const int y  = n >> 7;             // HW_ = 2^7
    const int xc = n & (HW_ - 1);
    const int c  = c4 << 2;

    // slab index -> offset
    int s;
    if (c < 256)      s = c >> 6;
    else if (c < 512) s = 4 + ((c - 256) >> 5);
    else              s = 12 + ((c - 512) >> 4);
    const int dy = (int)g_dy[s];
    const int dx = (int)g_dx[s];

    // self load: flat float index = 4*idx (contiguous within each XCD chunk)
    const f32x4 self = *reinterpret_cast<const f32x4*>(in + (size_t)idx * 4);

    const int sy = y - dy;
    const int sx = xc - dx;
    f32x4 sh = (f32x4){0.f, 0.f, 0.f, 0.f};
    if ((unsigned)sy < (unsigned)HW_ && (unsigned)sx < (unsigned)HW_) {
        const size_t sidx = ((size_t)(b * N_ + (sy << 7) + sx)) * C_ + c;
        sh = *reinterpret_cast<const f32x4*>(in + sidx);
    }

    f32x4 o;
    o.x = w * sh.x + omw * self.x;
    o.y = w * sh.y + omw * self.y;
    o.z = w * sh.z + omw * self.z;
    o.w = w * sh.w + omw * self.w;
    // streaming store: output is never re-read; keep L2/L3 for the input
    __builtin_nontemporal_store(o, reinterpret_cast<f32x4*>(out + (size_t)idx * 4));
}

extern "C" void kernel_launch(void* const* d_in, const int* in_sizes, int n_in,
                              void* d_out, int out_size, void* d_ws, size_t ws_size,
                              hipStream_t stream) {
    const float* x = (const float*)d_in[0];
    const float* w = (const float*)d_in[1];
    float* out = (float*)d_out;

    const int total4 = B_ * N_ * C4_;          // 18,874,368 float4 chunks
    const int blocks = total4 / 256;           // 73,728 (exact, divisible by 8)
    cgts_kernel<<<blocks, 256, 0, stream>>>(x, w, out);
}